// Round 15
// baseline (1032.923 us; speedup 1.0000x reference)
//
#include <hip/hip_runtime.h>

typedef unsigned short u16;
typedef unsigned int u32;

#define N_ATOMS 100000
#define N_BONDS 200000
#define N_EDGES 100000
#define HIDDEN 300
#define HP 320
#define ATOM_FDIM 133
#define BOND_FDIM 147
#define CATP 448
#define N_MOLS 2000

typedef __bf16 bf16x8 __attribute__((ext_vector_type(8)));
typedef float f32x4 __attribute__((ext_vector_type(4)));

__device__ __forceinline__ u16 f2bf(float f) {
    union { float f; u32 u; } x; x.f = f;
    u32 u = x.u;
    u32 r = u + 0x7fffu + ((u >> 16) & 1u);
    return (u16)(r >> 16);
}
__device__ __forceinline__ float bf2f(u16 h) {
    union { u32 u; float f; } x; x.u = ((u32)h) << 16;
    return x.f;
}

union U8 { uint4 v; u16 h[8]; };
union U4 { uint2 v; u16 h[4]; };

// async global->LDS, 16B per lane, LDS dest = base + lane*16 (HW-fixed)
#define GL16(gp, lp) __builtin_amdgcn_global_load_lds( \
    (const __attribute__((address_space(1))) u32*)(gp), \
    (__attribute__((address_space(3))) u32*)(lp), 16, 0, 0)

// ===== m97-style GEMM + counted-vmcnt 3-buffer pipeline (T3/T4 minimum) =====
// 128x64 tile, 256 threads = 4 waves (2x2). Per k-step each wave issues
// 2 A + 1 B global_load_lds into ring buffer (ks+2); then waits vmcnt(6)
// (2 stages in flight, NEVER 0 mid-loop), raw s_barrier, ds_read + 8 MFMA,
// raw s_barrier. A must be LINEAR bf16 (stride LDA, K=KSTEPS*32<=LDA).
// N-fastest + bijective XCD swizzle. Swapped-operand MFMA (lane = 4 cols).
// EP 1: O1=bf16(acc); EP 2: O1=bf16(acc+inp_in) (pre-issued);
// EP 3: O1=bf16(relu(acc+(col<Nout?bias:0)))
// EP 4: merged head via LDS-bounce: col<133 -> F1=acc+bias;
//       133<=col<147 -> F2[row*16+col-133]=acc+bias2
template<int EP, int KSTEPS, int LDA, int NB>
__global__ __launch_bounds__(256, 4) void k_gemmG(
    const u16* __restrict__ A, int M,
    const u16* __restrict__ Bt, int ldb, int Nout,
    const float* __restrict__ bias, const float* __restrict__ bias2,
    u16* __restrict__ O1, float* __restrict__ F1, float* __restrict__ F2,
    const u16* __restrict__ inp_in, int nwg)
{
    // per-buffer: A 128x32 (4096 u16) + B 64x32 (2048 u16) = 6144 u16
    __shared__ __align__(16) u16 SM[3 * 6144];

    // bijective XCD-chunk swizzle (m204)
    const int bid = blockIdx.x;
    const int q = nwg >> 3, r = nwg & 7;
    const int xcd = bid & 7, sidx = bid >> 3;
    const int wg = (xcd < r ? xcd * (q + 1) : r * (q + 1) + (xcd - r) * q) + sidx;

    const int n0 = (wg % NB) * 64;
    const int row0 = (wg / NB) * 128;

    const int tid = threadIdx.x;
    const int lane = tid & 63;
    const int wv = tid >> 6;
    const int wr = wv >> 1, wc = wv & 1;
    const int lrow = lane & 15;
    const int g = lane >> 4;

    // staging lane map: one GL16 covers 16 rows; lane l -> row +(l>>2), chunk l&3
    const int lr = lane >> 2, lc = lane & 3;
    int arow0 = row0 + wv * 32 + lr;
    int arow1 = arow0 + 16;
    if (arow0 >= M) arow0 = M - 1;
    if (arow1 >= M) arow1 = M - 1;
    const u16* gA0 = A + (size_t)arow0 * LDA + lc * 8;
    const u16* gA1 = A + (size_t)arow1 * LDA + lc * 8;
    const u16* gB  = Bt + (size_t)(n0 + wv * 16 + lr) * ldb + lc * 8;

    // EP2: pre-issue epilogue inp loads (oldest in vmcnt queue -> safe)
    U4 ii[8];
    if constexpr (EP == 2) {
#pragma unroll
        for (int m = 0; m < 4; m++) {
            const int row = row0 + wr * 64 + m * 16 + lrow;
#pragma unroll
            for (int n = 0; n < 2; n++) {
                if (row < M)
                    ii[m * 2 + n].v = *(const uint2*)&inp_in[
                        (size_t)row * HP + n0 + wc * 32 + n * 16 + g * 4];
            }
        }
    }

    auto STAGE = [&](int p, int ks) {
        const int k0 = ks * 32;
        u16* base = SM + p * 6144;
        GL16(gA0 + k0, base + wv * 1024);
        GL16(gA1 + k0, base + wv * 1024 + 512);
        GL16(gB  + k0, base + 4096 + wv * 512);
    };

    f32x4 acc[4][2] = {};

    STAGE(0, 0);
    if constexpr (KSTEPS > 1) STAGE(1, 1);

#pragma unroll
    for (int ks = 0; ks < KSTEPS; ks++) {
        if (ks + 2 < KSTEPS) STAGE((ks + 2) % 3, ks + 2);
        // counted wait: current buffer's 3 loads done; 2 stages stay in flight
        if (ks + 2 < KSTEPS)      asm volatile("s_waitcnt vmcnt(6)" ::: "memory");
        else if (ks + 1 < KSTEPS) asm volatile("s_waitcnt vmcnt(3)" ::: "memory");
        else                      asm volatile("s_waitcnt vmcnt(0)" ::: "memory");
        __builtin_amdgcn_s_barrier();
        asm volatile("" ::: "memory");

        const u16* Asp = SM + (ks % 3) * 6144;
        const u16* Bsp = Asp + 4096;
        bf16x8 af[4], bfr[2];
#pragma unroll
        for (int m = 0; m < 4; m++)
            af[m] = *(const bf16x8*)&Asp[(wr * 64 + m * 16 + lrow) * 32 + g * 8];
#pragma unroll
        for (int n = 0; n < 2; n++)
            bfr[n] = *(const bf16x8*)&Bsp[(wc * 32 + n * 16 + lrow) * 32 + g * 8];
#pragma unroll
        for (int m = 0; m < 4; m++)
#pragma unroll
            for (int n = 0; n < 2; n++)
                acc[m][n] = __builtin_amdgcn_mfma_f32_16x16x32_bf16(bfr[n], af[m], acc[m][n], 0, 0, 0);

        asm volatile("" ::: "memory");
        __builtin_amdgcn_s_barrier();
        asm volatile("" ::: "memory");
    }

    if constexpr (EP == 4) {
        // LDS-bounce coalesced f32 epilogue: 32x64 slice per m, stride 68
        float* LDSf = (float*)SM;
#pragma unroll
        for (int m = 0; m < 4; m++) {
            __syncthreads();
#pragma unroll
            for (int n = 0; n < 2; n++)
                *(f32x4*)&LDSf[(size_t)(wr * 16 + lrow) * 68 + wc * 32 + n * 16 + g * 4] = acc[m][n];
            __syncthreads();
#pragma unroll
            for (int i = 0; i < 8; i++) {
                const int rl = wv + i * 4;                       // 0..31
                const int grow = row0 + ((rl & 16) ? 64 : 0) + m * 16 + (rl & 15);
                const float v = LDSf[(size_t)rl * 68 + lane];
                const int col = n0 + lane;                       // lane = column
                if (grow < M) {
                    if (col < 133) F1[(size_t)grow * 133 + col] = v + bias[col];
                    else if (col < 147) F2[(size_t)grow * 16 + (col - 133)] = v + bias2[col - 133];
                }
            }
        }
    } else {
#pragma unroll
        for (int m = 0; m < 4; m++) {
            const int row = row0 + wr * 64 + m * 16 + lrow;
            if (row >= M) continue;
#pragma unroll
            for (int n = 0; n < 2; n++) {
                const int colb = n0 + wc * 32 + n * 16 + g * 4;
                U4 o;
                if constexpr (EP == 1) {
#pragma unroll
                    for (int qq = 0; qq < 4; qq++) o.h[qq] = f2bf(acc[m][n][qq]);
                } else if constexpr (EP == 2) {
#pragma unroll
                    for (int qq = 0; qq < 4; qq++) o.h[qq] = f2bf(acc[m][n][qq] + bf2f(ii[m * 2 + n].h[qq]));
                } else {
#pragma unroll
                    for (int qq = 0; qq < 4; qq++) {
                        float x = acc[m][n][qq] + ((colb + qq) < Nout ? bias[colb + qq] : 0.f);
                        o.h[qq] = f2bf(fmaxf(x, 0.f));
                    }
                }
                *(uint2*)&O1[(size_t)row * HP + colb] = o.v;
            }
        }
    }
}

// ---------------- weight pack: Bt[n][k] = W[k][n], bf16, zero-padded ----------------
__global__ void k_pack_wt(const float* __restrict__ W, u16* __restrict__ Bt,
                          int K, int N, int Kp, int Np)
{
    int idx = blockIdx.x * 256 + threadIdx.x;
    if (idx >= Np * Kp) return;
    int n = idx / Kp, k = idx - n * Kp;
    Bt[idx] = (n < N && k < K) ? f2bf(W[(size_t)k * N + n]) : (u16)0;
}

// W_o pack with the [amsg(300) | pad4 | f_atoms(133) | pad] column reorder
__global__ void k_pack_wo(const float* __restrict__ W, u16* __restrict__ Bt)
{
    int idx = blockIdx.x * 256 + threadIdx.x;
    if (idx >= 320 * CATP) return;
    int n = idx / CATP, k = idx - n * CATP;
    float v = 0.f;
    if (n < HIDDEN) {
        if (k < HIDDEN) v = W[(size_t)(ATOM_FDIM + k) * HIDDEN + n];
        else if (k >= 304 && k < 304 + ATOM_FDIM) v = W[(size_t)(k - 304) * HIDDEN + n];
    }
    Bt[idx] = f2bf(v);
}

// merged head pack: Bt_ne[n][k]: n<133 from W_node, 133<=n<147 from W_edge
__global__ void k_pack_wne(const float* __restrict__ Wn, const float* __restrict__ We,
                           u16* __restrict__ Bt)
{
    int idx = blockIdx.x * 256 + threadIdx.x;
    if (idx >= 320 * 320) return;
    int n = idx / 320, k = idx - n * 320;
    float v = 0.f;
    if (k < HIDDEN) {
        if (n < ATOM_FDIM) v = Wn[(size_t)k * ATOM_FDIM + n];
        else if (n < ATOM_FDIM + 14) v = We[(size_t)k * 14 + (n - ATOM_FDIM)];
    }
    Bt[idx] = f2bf(v);
}

// ---------------- f_bonds fp32 [B][147] -> bf16 [B][160] ----------------
__global__ __launch_bounds__(256) void k_pack_bonds(const float* __restrict__ fb, u16* __restrict__ out)
{
    int idx = blockIdx.x * 256 + threadIdx.x;
    if (idx >= N_BONDS * 20) return;
    int b = idx / 20, c0 = (idx - b * 20) * 8;
    U8 u;
#pragma unroll
    for (int e = 0; e < 8; e++) {
        int col = c0 + e;
        u.h[e] = (col < BOND_FDIM) ? f2bf(fb[(size_t)b * BOND_FDIM + col]) : (u16)0;
    }
    *(uint4*)&out[(size_t)b * 160 + c0] = u.v;
}

// ---------------- fill catbuf cols 304..447 with bf16 f_atoms ----------------
__global__ __launch_bounds__(256) void k_cat_fa(const float* __restrict__ fa, u16* __restrict__ cat)
{
    int idx = blockIdx.x * 256 + threadIdx.x;
    if (idx >= N_ATOMS * 18) return;
    int a = idx / 18, c0 = 304 + (idx - a * 18) * 8;
    U8 u;
#pragma unroll
    for (int e = 0; e < 8; e++) {
        int fc = c0 + e - 304;
        u.h[e] = (fc < ATOM_FDIM) ? f2bf(fa[(size_t)a * ATOM_FDIM + fc]) : (u16)0;
    }
    *(uint4*)&cat[(size_t)a * CATP + c0] = u.v;
}

// ---------------- a_msg[a] = sum_j relu(h[a2b[a][j]]), output stride OST ----------------
template<int OST>
__global__ __launch_bounds__(256) void k_aggregate(const u16* __restrict__ h,
    const int* __restrict__ a2b, u16* __restrict__ amsg)
{
    int idx = blockIdx.x * 256 + threadIdx.x;
    if (idx >= N_ATOMS * 40) return;
    int a = idx / 40, c = (idx - a * 40) * 8;
    float s[8] = {};
#pragma unroll
    for (int j = 0; j < 6; j++) {
        int b = a2b[a * 6 + j];
        U8 u; u.v = *(const uint4*)&h[(size_t)b * HP + c];
#pragma unroll
        for (int i = 0; i < 8; i++) s[i] += fmaxf(bf2f(u.h[i]), 0.f);
    }
    U8 o;
#pragma unroll
    for (int i = 0; i < 8; i++) o.h[i] = f2bf(s[i]);
    *(uint4*)&amsg[(size_t)a * OST + c] = o.v;
}

// -------- delta[b] = amsg[b2a[b]] - relu(h[b^1])   (streaming, gathers here) --------
__global__ __launch_bounds__(256) void k_delta(const u16* __restrict__ amsg,
    const u16* __restrict__ h, const int* __restrict__ b2a, u16* __restrict__ dlt)
{
    int idx = blockIdx.x * 256 + threadIdx.x;
    if (idx >= N_BONDS * 40) return;
    int b = idx / 40, c = (idx - b * 40) * 8;
    int a = b2a[b];
    U8 x; x.v = *(const uint4*)&amsg[(size_t)a * HP + c];
    U8 y; y.v = *(const uint4*)&h[(size_t)(b ^ 1) * HP + c];
    U8 o;
#pragma unroll
    for (int i = 0; i < 8; i++)
        o.h[i] = f2bf(bf2f(x.h[i]) - fmaxf(bf2f(y.h[i]), 0.f));
    *(uint4*)&dlt[(size_t)b * HP + c] = o.v;
}

// -------- edge head finish: out[e] = 0.5*(E[b2a[2e]] + E[b2a[2e+1]]) --------
__global__ __launch_bounds__(256) void k_edge(const float* __restrict__ E,
    const int* __restrict__ b2a, float* __restrict__ out)
{
    int idx = blockIdx.x * 256 + threadIdx.x;
    if (idx >= N_EDGES * 7) return;
    int e = idx / 7, p = idx - e * 7;
    int a1 = b2a[2 * e], a2 = b2a[2 * e + 1];
    float2 x = *(const float2*)&E[(size_t)a1 * 16 + 2 * p];
    float2 y = *(const float2*)&E[(size_t)a2 * 16 + 2 * p];
    float2 o; o.x = 0.5f * (x.x + y.x); o.y = 0.5f * (x.y + y.y);
    *(float2*)&out[(size_t)e * 14 + 2 * p] = o;
}

// ---------------- per-molecule segment sum (graph_idx sorted) ----------------
__device__ __forceinline__ int lower_bound_i(const int* a, int n, int v) {
    int lo = 0, hi = n;
    while (lo < hi) { int mid = (lo + hi) >> 1; if (a[mid] < v) lo = mid + 1; else hi = mid; }
    return lo;
}
__global__ __launch_bounds__(320) void k_segsum(const u16* __restrict__ ah,
    const int* __restrict__ gidx, float* __restrict__ gemb)
{
    int g = blockIdx.x;
    int c = threadIdx.x;
    int s = lower_bound_i(gidx, N_ATOMS, g);
    int e = lower_bound_i(gidx, N_ATOMS, g + 1);
    float sum = 0.f;
    for (int a = s; a < e; a++) sum += bf2f(ah[(size_t)a * HP + c]);
    gemb[(size_t)g * HP + c] = sum;
}

// ---------------- graph head (fp32) ----------------
__global__ __launch_bounds__(320) void k_g1(const float* __restrict__ gemb,
    const float* __restrict__ W, const float* __restrict__ b, float* __restrict__ gh)
{
    int g = blockIdx.x, j = threadIdx.x;
    float acc = 0.f;
    if (j < HIDDEN) {
        acc = b[j];
        for (int k = 0; k < HIDDEN; k++)
            acc = fmaf(gemb[(size_t)g * HP + k], W[(size_t)k * HIDDEN + j], acc);
        acc = fmaxf(acc, 0.f);
    }
    gh[(size_t)g * HP + j] = (j < HIDDEN) ? acc : 0.f;
}
__global__ __launch_bounds__(64) void k_g2(const float* __restrict__ gh,
    const float* __restrict__ W, const float* __restrict__ b, float* __restrict__ out)
{
    int g = blockIdx.x, l = threadIdx.x;
    float acc = 0.f;
    for (int j = l; j < HIDDEN; j += 64) acc += gh[(size_t)g * HP + j] * W[j];
#pragma unroll
    for (int off = 32; off; off >>= 1) acc += __shfl_down(acc, off, 64);
    if (l == 0) out[g] = acc + b[0];
}

extern "C" void kernel_launch(void* const* d_in, const int* in_sizes, int n_in,
                              void* d_out, int out_size, void* d_ws, size_t ws_size,
                              hipStream_t stream)
{
    const float* f_atoms = (const float*)d_in[0];
    const float* f_bonds = (const float*)d_in[1];
    const int* a2b    = (const int*)d_in[2];
    const int* b2a    = (const int*)d_in[3];
    const int* gidx   = (const int*)d_in[5];
    const float* W_i    = (const float*)d_in[6];
    const float* W_h    = (const float*)d_in[7];
    const float* W_o    = (const float*)d_in[8];
    const float* b_o    = (const float*)d_in[9];
    const float* W_node = (const float*)d_in[10];
    const float* b_node = (const float*)d_in[11];
    const float* W_edge = (const float*)d_in[12];
    const float* b_edge = (const float*)d_in[13];
    const float* W_g1   = (const float*)d_in[14];
    const float* b_g1   = (const float*)d_in[15];
    const float* W_g2   = (const float*)d_in[16];
    const float* b_g2   = (const float*)d_in[17];

    char* ws = (char*)d_ws;
    u16* inp   = (u16*)(ws + 0);            // 128 MB: h1 pre-relu; later catbuf
    u16* hA    = (u16*)(ws + 128000000);    // 128 MB: fb16 pack -> h2/h3
    u16* hB    = (u16*)(ws + 256000000);    // 128 MB: delta scratch -> ah
    u16* amsg  = (u16*)(ws + 384000000);    // 64 MB: amsg -> Ebuf
    u16* wt_i  = (u16*)(ws + 448000000);    // 320x160
    u16* wt_h  = (u16*)(ws + 448200000);    // 320x320
    u16* wt_o  = (u16*)(ws + 448500000);    // 320x448
    u16* wt_ne = (u16*)(ws + 448800000);    // 320x320
    float* gemb = (float*)(ws + 449300000); // 2000x320 f32
    float* gh   = (float*)(ws + 452000000); // 2000x320 f32

    float* out_node  = (float*)d_out;
    float* out_edge  = out_node + (size_t)N_ATOMS * ATOM_FDIM;
    float* out_graph = out_node + 14700000;

    dim3 blk(256);

    // pack weights (bf16, transposed, zero-padded)
    k_pack_wt<<<(320 * 160 + 255) / 256, blk, 0, stream>>>(W_i, wt_i, BOND_FDIM, HIDDEN, 160, 320);
    k_pack_wt<<<(320 * 320 + 255) / 256, blk, 0, stream>>>(W_h, wt_h, HIDDEN, HIDDEN, 320, 320);
    k_pack_wo<<<(320 * CATP + 255) / 256, blk, 0, stream>>>(W_o, wt_o);
    k_pack_wne<<<(320 * 320 + 255) / 256, blk, 0, stream>>>(W_node, W_edge, wt_ne);

    const int mbB = (N_BONDS + 127) / 128;  // 1563
    const int mbA = (N_ATOMS + 127) / 128;  // 782
    const int gAg = (N_ATOMS * 40 + 255) / 256;
    const int gDl = (N_BONDS * 40 + 255) / 256;
    const int nwgI = 5 * mbB;
    const int nwgO = 5 * mbA;
    const int nwgH = 3 * mbA;

    // pack f_bonds -> bf16[200k][160] into hA (dead until depth-1 GEMM output)
    u16* fb16 = hA;
    k_pack_bonds<<<(N_BONDS * 20 + 255) / 256, blk, 0, stream>>>(f_bonds, fb16);

    // inp = f_bonds @ W_i  (pre-relu stored)
    k_gemmG<1, 5, 160, 5><<<nwgI, blk, 0, stream>>>(
        fb16, N_BONDS, wt_i, 160, 0, nullptr, nullptr,
        inp, nullptr, nullptr, nullptr, nwgI);

    // depth loop: h' = inp + delta @ W_h; delta built by streaming kernel
    const u16* hcur = inp;
    for (int d = 0; d < 2; ++d) {
        k_aggregate<HP><<<gAg, blk, 0, stream>>>(hcur, a2b, amsg);
        k_delta<<<gDl, blk, 0, stream>>>(amsg, hcur, b2a, hB);
        k_gemmG<2, 10, 320, 5><<<nwgI, blk, 0, stream>>>(
            hB, N_BONDS, wt_h, 320, 0, nullptr, nullptr,
            hA, nullptr, nullptr, inp, nwgI);
        hcur = hA;
    }

    // final aggregate -> catbuf (stride 448, cols 0..319; 300+ are zeros),
    // then fill cols 304..447 with bf16 f_atoms
    u16* catbuf = inp;   // inp dead after depth-2 GEMM
    k_aggregate<CATP><<<gAg, blk, 0, stream>>>(hcur, a2b, catbuf);
    k_cat_fa<<<(N_ATOMS * 18 + 255) / 256, blk, 0, stream>>>(f_atoms, catbuf);

    // atom_hiddens = relu(cat @ W_o + b_o) -> ah (bf16) in hB
    u16* ah = hB;
    k_gemmG<3, 14, 448, 5><<<nwgO, blk, 0, stream>>>(
        catbuf, N_ATOMS, wt_o, CATP, HIDDEN, b_o, nullptr,
        ah, nullptr, nullptr, nullptr, nwgO);

    // merged node+edge head: cols 0..132 -> node preds, 133..146 -> E buffer
    float* Ebuf = (float*)amsg;   // amsg dead after last k_delta
    k_gemmG<4, 10, 320, 3><<<nwgH, blk, 0, stream>>>(
        ah, N_ATOMS, wt_ne, 320, 0, b_node, b_edge,
        nullptr, out_node, Ebuf, nullptr, nwgH);

    // edge head finish: average endpoint E rows
    k_edge<<<(N_EDGES * 7 + 255) / 256, blk, 0, stream>>>(Ebuf, b2a, out_edge);

    // graph head
    k_segsum<<<N_MOLS, 320, 0, stream>>>(ah, gidx, gemb);
    k_g1<<<N_MOLS, 320, 0, stream>>>(gemb, W_g1, b_g1, gh);
    k_g2<<<N_MOLS, 64, 0, stream>>>(gh, W_g2, b_g2, out_graph);
}

// Round 16
// 970.657 us; speedup vs baseline: 1.0641x; 1.0641x over previous
//
#include <hip/hip_runtime.h>

typedef unsigned short u16;
typedef unsigned int u32;

#define N_ATOMS 100000
#define N_BONDS 200000
#define N_EDGES 100000
#define HIDDEN 300
#define HP 320
#define ATOM_FDIM 133
#define BOND_FDIM 147
#define CATP 448
#define N_MOLS 2000

typedef __bf16 bf16x8 __attribute__((ext_vector_type(8)));
typedef float f32x4 __attribute__((ext_vector_type(4)));

__device__ __forceinline__ u16 f2bf(float f) {
    union { float f; u32 u; } x; x.f = f;
    u32 u = x.u;
    u32 r = u + 0x7fffu + ((u >> 16) & 1u);
    return (u16)(r >> 16);
}
__device__ __forceinline__ float bf2f(u16 h) {
    union { u32 u; float f; } x; x.u = ((u32)h) << 16;
    return x.f;
}

union U8 { uint4 v; u16 h[8]; };
union U4 { uint2 v; u16 h[4]; };

// async global->LDS, 16B per lane, LDS dest = base + lane*16 (HW-fixed);
// the GLOBAL address is per-lane (gather allowed).
#define GL16(gp, lp) __builtin_amdgcn_global_load_lds( \
    (const __attribute__((address_space(1))) u32*)(gp), \
    (__attribute__((address_space(3))) u32*)(lp), 16, 0, 0)

// ===== m97-style GEMM: 128x64 tile, global_load_lds staging (R14 core) =====
// 256 threads = 4 waves (2x2). Per k-step: issue GL16 stages, __syncthreads
// (drain), ds_read + MFMA, __syncthreads. N-fastest + bijective XCD swizzle.
// Swapped-operand MFMA: lane holds 4 consecutive output cols.
// DSRC 0: single linear A (stride LDA).
// DSRC 2: fused bond-message A: acc = amsg[i1[r]]@W - msg[r^1]@W via TWO
//         MFMAs (second with sign-negated B frag). Gathered X rows staged
//         via per-lane GL16 addresses; both strides = HP.
// EP 1: O1=bf16(acc)
// EP 3: O1=bf16(relu(acc + (col<Nout?bias:0)))
// EP 4: merged head via LDS-bounce: col<133 -> F1=acc+bias[col];
//       133<=col<147 -> F2[row*16+col-133]=acc+bias2[col-133]
// EP 5: O1=bf16(relu(acc + inp_in))    (msg epilogue, post-relu store)
// EP 6: O1=bf16(acc); O2=bf16(relu(acc))   (W_i dual store)
template<int DSRC, int EP, int KSTEPS, int LDA, int NB>
__global__ __launch_bounds__(256, 4) void k_gemmG(
    const u16* __restrict__ A, const u16* __restrict__ Y,
    const int* __restrict__ i1, int M,
    const u16* __restrict__ Bt, int ldb, int Nout,
    const float* __restrict__ bias, const float* __restrict__ bias2,
    u16* __restrict__ O1, u16* __restrict__ O2,
    float* __restrict__ F1, float* __restrict__ F2,
    const u16* __restrict__ inp_in, int nwg)
{
    // DSRC0: A 128x32 + B 64x32 = 6144 u16. DSRC2: X + Y + B = 10240 u16.
    constexpr int SMU = (DSRC == 2) ? 10240 : 6144;
    __shared__ __align__(16) u16 SM[SMU];

    // bijective XCD-chunk swizzle (m204)
    const int bid = blockIdx.x;
    const int q = nwg >> 3, r = nwg & 7;
    const int xcd = bid & 7, sidx = bid >> 3;
    const int wg = (xcd < r ? xcd * (q + 1) : r * (q + 1) + (xcd - r) * q) + sidx;

    const int n0 = (wg % NB) * 64;
    const int row0 = (wg / NB) * 128;

    const int tid = threadIdx.x;
    const int lane = tid & 63;
    const int wv = tid >> 6;
    const int wr = wv >> 1, wc = wv & 1;
    const int lrow = lane & 15;
    const int g = lane >> 4;

    // staging lane map: one GL16 covers 16 rows; lane l -> row +(l>>2), chunk l&3
    const int lr = lane >> 2, lc = lane & 3;
    int arow0 = row0 + wv * 32 + lr;
    int arow1 = arow0 + 16;
    if (arow0 >= M) arow0 = M - 1;
    if (arow1 >= M) arow1 = M - 1;

    const u16* gA0; const u16* gA1;
    const u16* gY0 = nullptr; const u16* gY1 = nullptr;
    if constexpr (DSRC == 2) {
        gA0 = A + (size_t)i1[arow0] * HP + lc * 8;   // gathered amsg rows
        gA1 = A + (size_t)i1[arow1] * HP + lc * 8;
        gY0 = Y + (size_t)(arow0 ^ 1) * HP + lc * 8; // reverse-bond msg rows
        gY1 = Y + (size_t)(arow1 ^ 1) * HP + lc * 8;
    } else {
        gA0 = A + (size_t)arow0 * LDA + lc * 8;
        gA1 = A + (size_t)arow1 * LDA + lc * 8;
    }
    const u16* gB = Bt + (size_t)(n0 + wv * 16 + lr) * ldb + lc * 8;

    constexpr int BOFF = (DSRC == 2) ? 8192 : 4096;

    // EP5: pre-issue epilogue inp loads (oldest in queue; drained by 1st sync)
    U4 ii[8];
    if constexpr (EP == 5) {
#pragma unroll
        for (int m = 0; m < 4; m++) {
            const int row = row0 + wr * 64 + m * 16 + lrow;
#pragma unroll
            for (int n = 0; n < 2; n++) {
                if (row < M)
                    ii[m * 2 + n].v = *(const uint2*)&inp_in[
                        (size_t)row * HP + n0 + wc * 32 + n * 16 + g * 4];
            }
        }
    }

    f32x4 acc[4][2] = {};

#pragma unroll
    for (int ks = 0; ks < KSTEPS; ks++) {
        const int k0 = ks * 32;
        GL16(gA0 + k0, SM + wv * 1024);
        GL16(gA1 + k0, SM + wv * 1024 + 512);
        if constexpr (DSRC == 2) {
            GL16(gY0 + k0, SM + 4096 + wv * 1024);
            GL16(gY1 + k0, SM + 4096 + wv * 1024 + 512);
        }
        GL16(gB + k0, SM + BOFF + wv * 512);
        __syncthreads();

        bf16x8 bfr[2];
#pragma unroll
        for (int n = 0; n < 2; n++)
            bfr[n] = *(const bf16x8*)&SM[BOFF + (wc * 32 + n * 16 + lrow) * 32 + g * 8];

        bf16x8 af[4];
#pragma unroll
        for (int m = 0; m < 4; m++)
            af[m] = *(const bf16x8*)&SM[(wr * 64 + m * 16 + lrow) * 32 + g * 8];

        if constexpr (DSRC == 2) {
            bf16x8 yf[4], bneg[2];
#pragma unroll
            for (int m = 0; m < 4; m++)
                yf[m] = *(const bf16x8*)&SM[4096 + (wr * 64 + m * 16 + lrow) * 32 + g * 8];
#pragma unroll
            for (int n = 0; n < 2; n++) {
                uint4 bu = *(uint4*)&bfr[n];
                bu.x ^= 0x80008000u; bu.y ^= 0x80008000u;
                bu.z ^= 0x80008000u; bu.w ^= 0x80008000u;
                bneg[n] = *(bf16x8*)&bu;
            }
#pragma unroll
            for (int m = 0; m < 4; m++)
#pragma unroll
                for (int n = 0; n < 2; n++) {
                    acc[m][n] = __builtin_amdgcn_mfma_f32_16x16x32_bf16(bfr[n], af[m], acc[m][n], 0, 0, 0);
                    acc[m][n] = __builtin_amdgcn_mfma_f32_16x16x32_bf16(bneg[n], yf[m], acc[m][n], 0, 0, 0);
                }
        } else {
#pragma unroll
            for (int m = 0; m < 4; m++)
#pragma unroll
                for (int n = 0; n < 2; n++)
                    acc[m][n] = __builtin_amdgcn_mfma_f32_16x16x32_bf16(bfr[n], af[m], acc[m][n], 0, 0, 0);
        }
        __syncthreads();
    }

    if constexpr (EP == 4) {
        // LDS-bounce coalesced f32 epilogue: 32x64 slice per m, stride 68
        float* LDSf = (float*)SM;   // 8704 B <= 12288 B
#pragma unroll
        for (int m = 0; m < 4; m++) {
            __syncthreads();
#pragma unroll
            for (int n = 0; n < 2; n++)
                *(f32x4*)&LDSf[(size_t)(wr * 16 + lrow) * 68 + wc * 32 + n * 16 + g * 4] = acc[m][n];
            __syncthreads();
#pragma unroll
            for (int i = 0; i < 8; i++) {
                const int rl = wv + i * 4;                       // 0..31
                const int grow = row0 + ((rl & 16) ? 64 : 0) + m * 16 + (rl & 15);
                const float v = LDSf[(size_t)rl * 68 + lane];
                const int col = n0 + lane;                       // lane = column
                if (grow < M) {
                    if (col < 133) F1[(size_t)grow * 133 + col] = v + bias[col];
                    else if (col < 147) F2[(size_t)grow * 16 + (col - 133)] = v + bias2[col - 133];
                }
            }
        }
    } else {
#pragma unroll
        for (int m = 0; m < 4; m++) {
            const int row = row0 + wr * 64 + m * 16 + lrow;
            if (row >= M) continue;
#pragma unroll
            for (int n = 0; n < 2; n++) {
                const int colb = n0 + wc * 32 + n * 16 + g * 4;
                U4 o;
                if constexpr (EP == 1) {
#pragma unroll
                    for (int qq = 0; qq < 4; qq++) o.h[qq] = f2bf(acc[m][n][qq]);
                    *(uint2*)&O1[(size_t)row * HP + colb] = o.v;
                } else if constexpr (EP == 5) {
#pragma unroll
                    for (int qq = 0; qq < 4; qq++)
                        o.h[qq] = f2bf(fmaxf(acc[m][n][qq] + bf2f(ii[m * 2 + n].h[qq]), 0.f));
                    *(uint2*)&O1[(size_t)row * HP + colb] = o.v;
                } else if constexpr (EP == 6) {
                    U4 o2;
#pragma unroll
                    for (int qq = 0; qq < 4; qq++) {
                        o.h[qq] = f2bf(acc[m][n][qq]);
                        o2.h[qq] = f2bf(fmaxf(acc[m][n][qq], 0.f));
                    }
                    *(uint2*)&O1[(size_t)row * HP + colb] = o.v;
                    *(uint2*)&O2[(size_t)row * HP + colb] = o2.v;
                } else {
#pragma unroll
                    for (int qq = 0; qq < 4; qq++) {
                        float x = acc[m][n][qq] + ((colb + qq) < Nout ? bias[colb + qq] : 0.f);
                        o.h[qq] = f2bf(fmaxf(x, 0.f));
                    }
                    *(uint2*)&O1[(size_t)row * HP + colb] = o.v;
                }
            }
        }
    }
}

// ---------------- weight pack: Bt[n][k] = W[k][n], bf16, zero-padded ----------------
__global__ void k_pack_wt(const float* __restrict__ W, u16* __restrict__ Bt,
                          int K, int N, int Kp, int Np)
{
    int idx = blockIdx.x * 256 + threadIdx.x;
    if (idx >= Np * Kp) return;
    int n = idx / Kp, k = idx - n * Kp;
    Bt[idx] = (n < N && k < K) ? f2bf(W[(size_t)k * N + n]) : (u16)0;
}

// W_o pack with the [amsg(300) | pad4 | f_atoms(133) | pad] column reorder
__global__ void k_pack_wo(const float* __restrict__ W, u16* __restrict__ Bt)
{
    int idx = blockIdx.x * 256 + threadIdx.x;
    if (idx >= 320 * CATP) return;
    int n = idx / CATP, k = idx - n * CATP;
    float v = 0.f;
    if (n < HIDDEN) {
        if (k < HIDDEN) v = W[(size_t)(ATOM_FDIM + k) * HIDDEN + n];
        else if (k >= 304 && k < 304 + ATOM_FDIM) v = W[(size_t)(k - 304) * HIDDEN + n];
    }
    Bt[idx] = f2bf(v);
}

// merged head pack: Bt_ne[n][k]: n<133 from W_node, 133<=n<147 from W_edge
__global__ void k_pack_wne(const float* __restrict__ Wn, const float* __restrict__ We,
                           u16* __restrict__ Bt)
{
    int idx = blockIdx.x * 256 + threadIdx.x;
    if (idx >= 320 * 320) return;
    int n = idx / 320, k = idx - n * 320;
    float v = 0.f;
    if (k < HIDDEN) {
        if (n < ATOM_FDIM) v = Wn[(size_t)k * ATOM_FDIM + n];
        else if (n < ATOM_FDIM + 14) v = We[(size_t)k * 14 + (n - ATOM_FDIM)];
    }
    Bt[idx] = f2bf(v);
}

// ---------------- f_bonds fp32 [B][147] -> bf16 [B][160] ----------------
__global__ __launch_bounds__(256) void k_pack_bonds(const float* __restrict__ fb, u16* __restrict__ out)
{
    int idx = blockIdx.x * 256 + threadIdx.x;
    if (idx >= N_BONDS * 20) return;
    int b = idx / 20, c0 = (idx - b * 20) * 8;
    U8 u;
#pragma unroll
    for (int e = 0; e < 8; e++) {
        int col = c0 + e;
        u.h[e] = (col < BOND_FDIM) ? f2bf(fb[(size_t)b * BOND_FDIM + col]) : (u16)0;
    }
    *(uint4*)&out[(size_t)b * 160 + c0] = u.v;
}

// --------- a_msg[a] = sum_j msg[a2b[a][j]] (plain sum, msg is post-relu) ---------
// OST 320: plain amsg. OST 448 + FA: catbuf with f_atoms cols fused.
template<int OST, int FA>
__global__ __launch_bounds__(256) void k_aggregate(const u16* __restrict__ msg,
    const int* __restrict__ a2b, const float* __restrict__ fa, u16* __restrict__ out)
{
    constexpr int CH = FA ? 56 : 40;
    int idx = blockIdx.x * 256 + threadIdx.x;
    if (idx >= N_ATOMS * CH) return;
    int a = idx / CH, cc = idx - a * CH;
    if (FA && cc >= 38) {
        // cols 304..447: bf16 f_atoms (133) then zeros
        int c0 = cc * 8 + (38 * 8 == 304 ? 0 : 0);   // cc in [38,56) -> col0 = cc*8
        c0 = cc * 8;
        U8 u;
#pragma unroll
        for (int e = 0; e < 8; e++) {
            int fc = c0 + e - 304;
            u.h[e] = (fc >= 0 && fc < ATOM_FDIM) ? f2bf(fa[(size_t)a * ATOM_FDIM + fc]) : (u16)0;
        }
        *(uint4*)&out[(size_t)a * OST + c0] = u.v;
        return;
    }
    int c = cc * 8;
    float s[8] = {};
#pragma unroll
    for (int j = 0; j < 6; j++) {
        int b = a2b[a * 6 + j];
        U8 u; u.v = *(const uint4*)&msg[(size_t)b * HP + c];
#pragma unroll
        for (int i = 0; i < 8; i++) s[i] += bf2f(u.h[i]);
    }
    U8 o;
#pragma unroll
    for (int i = 0; i < 8; i++) o.h[i] = f2bf(s[i]);
    *(uint4*)&out[(size_t)a * OST + c] = o.v;
}

// -------- edge head finish: out[e] = 0.5*(E[b2a[2e]] + E[b2a[2e+1]]) --------
__global__ __launch_bounds__(256) void k_edge(const float* __restrict__ E,
    const int* __restrict__ b2a, float* __restrict__ out)
{
    int idx = blockIdx.x * 256 + threadIdx.x;
    if (idx >= N_EDGES * 7) return;
    int e = idx / 7, p = idx - e * 7;
    int a1 = b2a[2 * e], a2 = b2a[2 * e + 1];
    float2 x = *(const float2*)&E[(size_t)a1 * 16 + 2 * p];
    float2 y = *(const float2*)&E[(size_t)a2 * 16 + 2 * p];
    float2 o; o.x = 0.5f * (x.x + y.x); o.y = 0.5f * (x.y + y.y);
    *(float2*)&out[(size_t)e * 14 + 2 * p] = o;
}

// ---------------- per-molecule segment sum (graph_idx sorted) ----------------
__device__ __forceinline__ int lower_bound_i(const int* a, int n, int v) {
    int lo = 0, hi = n;
    while (lo < hi) { int mid = (lo + hi) >> 1; if (a[mid] < v) lo = mid + 1; else hi = mid; }
    return lo;
}
__global__ __launch_bounds__(320) void k_segsum(const u16* __restrict__ ah,
    const int* __restrict__ gidx, float* __restrict__ gemb)
{
    int g = blockIdx.x;
    int c = threadIdx.x;
    int s = lower_bound_i(gidx, N_ATOMS, g);
    int e = lower_bound_i(gidx, N_ATOMS, g + 1);
    float sum = 0.f;
    for (int a = s; a < e; a++) sum += bf2f(ah[(size_t)a * HP + c]);
    gemb[(size_t)g * HP + c] = sum;
}

// ---------------- graph head (fp32) ----------------
__global__ __launch_bounds__(320) void k_g1(const float* __restrict__ gemb,
    const float* __restrict__ W, const float* __restrict__ b, float* __restrict__ gh)
{
    int g = blockIdx.x, j = threadIdx.x;
    float acc = 0.f;
    if (j < HIDDEN) {
        acc = b[j];
        for (int k = 0; k < HIDDEN; k++)
            acc = fmaf(gemb[(size_t)g * HP + k], W[(size_t)k * HIDDEN + j], acc);
        acc = fmaxf(acc, 0.f);
    }
    gh[(size_t)g * HP + j] = (j < HIDDEN) ? acc : 0.f;
}
__global__ __launch_bounds__(64) void k_g2(const float* __restrict__ gh,
    const float* __restrict__ W, const float* __restrict__ b, float* __restrict__ out)
{
    int g = blockIdx.x, l = threadIdx.x;
    float acc = 0.f;
    for (int j = l; j < HIDDEN; j += 64) acc += gh[(size_t)g * HP + j] * W[j];
#pragma unroll
    for (int off = 32; off; off >>= 1) acc += __shfl_down(acc, off, 64);
    if (l == 0) out[g] = acc + b[0];
}

extern "C" void kernel_launch(void* const* d_in, const int* in_sizes, int n_in,
                              void* d_out, int out_size, void* d_ws, size_t ws_size,
                              hipStream_t stream)
{
    const float* f_atoms = (const float*)d_in[0];
    const float* f_bonds = (const float*)d_in[1];
    const int* a2b    = (const int*)d_in[2];
    const int* b2a    = (const int*)d_in[3];
    const int* gidx   = (const int*)d_in[5];
    const float* W_i    = (const float*)d_in[6];
    const float* W_h    = (const float*)d_in[7];
    const float* W_o    = (const float*)d_in[8];
    const float* b_o    = (const float*)d_in[9];
    const float* W_node = (const float*)d_in[10];
    const float* b_node = (const float*)d_in[11];
    const float* W_edge = (const float*)d_in[12];
    const float* b_edge = (const float*)d_in[13];
    const float* W_g1   = (const float*)d_in[14];
    const float* b_g1   = (const float*)d_in[15];
    const float* W_g2   = (const float*)d_in[16];
    const float* b_g2   = (const float*)d_in[17];

    char* ws = (char*)d_ws;
    u16* inp   = (u16*)(ws + 0);            // 128 MB: inp (pre-relu); later catbuf
    u16* msgA  = (u16*)(ws + 128000000);    // 128 MB: fb16 -> msg1 -> msg3
    u16* msgB  = (u16*)(ws + 256000000);    // 128 MB: msg2 -> ah
    u16* amsg  = (u16*)(ws + 384000000);    // 64 MB: amsg -> Ebuf
    u16* wt_i  = (u16*)(ws + 448000000);    // 320x160
    u16* wt_h  = (u16*)(ws + 448200000);    // 320x320
    u16* wt_o  = (u16*)(ws + 448500000);    // 320x448
    u16* wt_ne = (u16*)(ws + 448800000);    // 320x320
    float* gemb = (float*)(ws + 449300000); // 2000x320 f32
    float* gh   = (float*)(ws + 452000000); // 2000x320 f32

    float* out_node  = (float*)d_out;
    float* out_edge  = out_node + (size_t)N_ATOMS * ATOM_FDIM;
    float* out_graph = out_node + 14700000;

    dim3 blk(256);

    // pack weights (bf16, transposed, zero-padded)
    k_pack_wt<<<(320 * 160 + 255) / 256, blk, 0, stream>>>(W_i, wt_i, BOND_FDIM, HIDDEN, 160, 320);
    k_pack_wt<<<(320 * 320 + 255) / 256, blk, 0, stream>>>(W_h, wt_h, HIDDEN, HIDDEN, 320, 320);
    k_pack_wo<<<(320 * CATP + 255) / 256, blk, 0, stream>>>(W_o, wt_o);
    k_pack_wne<<<(320 * 320 + 255) / 256, blk, 0, stream>>>(W_node, W_edge, wt_ne);

    const int mbB = (N_BONDS + 127) / 128;  // 1563
    const int mbA = (N_ATOMS + 127) / 128;  // 782
    const int gAg = (N_ATOMS * 40 + 255) / 256;
    const int gAgF = (N_ATOMS * 56 + 255) / 256;
    const int nwgI = 5 * mbB;
    const int nwgO = 5 * mbA;
    const int nwgH = 3 * mbA;

    // pack f_bonds -> bf16[200k][160] into msgB (dead until msg2 written)
    u16* fb16 = msgB;
    k_pack_bonds<<<(N_BONDS * 20 + 255) / 256, blk, 0, stream>>>(f_bonds, fb16);

    // W_i dual-store: inp = f_bonds@W_i (pre-relu), msg1 = relu(inp)
    u16* msg1 = msgA;
    k_gemmG<0, 6, 5, 160, 5><<<nwgI, blk, 0, stream>>>(
        fb16, nullptr, nullptr, N_BONDS, wt_i, 160, 0, nullptr, nullptr,
        inp, msg1, nullptr, nullptr, nullptr, nwgI);

    // depth 1: amsg = sum msg1[a2b]; msg2 = relu(inp + amsg[b2a]@W - msg1[b^1]@W)
    k_aggregate<HP, 0><<<gAg, blk, 0, stream>>>(msg1, a2b, nullptr, amsg);
    u16* msg2 = msgB;
    k_gemmG<2, 5, 10, HP, 5><<<nwgI, blk, 0, stream>>>(
        amsg, msg1, b2a, N_BONDS, wt_h, 320, 0, nullptr, nullptr,
        msg2, nullptr, nullptr, nullptr, inp, nwgI);

    // depth 2: msg3 into msgA (msg1 dead)
    k_aggregate<HP, 0><<<gAg, blk, 0, stream>>>(msg2, a2b, nullptr, amsg);
    u16* msg3 = msgA;
    k_gemmG<2, 5, 10, HP, 5><<<nwgI, blk, 0, stream>>>(
        amsg, msg2, b2a, N_BONDS, wt_h, 320, 0, nullptr, nullptr,
        msg3, nullptr, nullptr, nullptr, inp, nwgI);

    // final aggregate -> catbuf (stride 448) with fused f_atoms fill
    u16* catbuf = inp;   // inp dead after depth-2 GEMM
    k_aggregate<CATP, 1><<<gAgF, blk, 0, stream>>>(msg3, a2b, f_atoms, catbuf);

    // atom_hiddens = relu(cat @ W_o + b_o) -> ah (bf16) in msgB
    u16* ah = msgB;
    k_gemmG<0, 3, 14, 448, 5><<<nwgO, blk, 0, stream>>>(
        catbuf, nullptr, nullptr, N_ATOMS, wt_o, CATP, HIDDEN, b_o, nullptr,
        ah, nullptr, nullptr, nullptr, nullptr, nwgO);

    // merged node+edge head: cols 0..132 -> node preds, 133..146 -> E buffer
    float* Ebuf = (float*)amsg;   // amsg dead after depth-2 GEMM
    k_gemmG<0, 4, 10, HP, 3><<<nwgH, blk, 0, stream>>>(
        ah, nullptr, nullptr, N_ATOMS, wt_ne, 320, 0, b_node, b_edge,
        nullptr, nullptr, out_node, Ebuf, nullptr, nwgH);

    // edge head finish: average endpoint E rows
    k_edge<<<(N_EDGES * 7 + 255) / 256, blk, 0, stream>>>(Ebuf, b2a, out_edge);

    // graph head
    k_segsum<<<N_MOLS, 320, 0, stream>>>(ah, gidx, gemb);
    k_g1<<<N_MOLS, 320, 0, stream>>>(gemb, W_g1, b_g1, gh);
    k_g2<<<N_MOLS, 64, 0, stream>>>(gh, W_g2, b_g2, out_graph);
}

// Round 17
// 958.025 us; speedup vs baseline: 1.0782x; 1.0132x over previous
//
#include <hip/hip_runtime.h>

typedef unsigned short u16;
typedef unsigned int u32;

#define N_ATOMS 100000
#define N_BONDS 200000
#define N_EDGES 100000
#define HIDDEN 300
#define HP 320
#define ATOM_FDIM 133
#define BOND_FDIM 147
#define CATP 448
#define N_MOLS 2000

typedef __bf16 bf16x8 __attribute__((ext_vector_type(8)));
typedef float f32x4 __attribute__((ext_vector_type(4)));

__device__ __forceinline__ u16 f2bf(float f) {
    union { float f; u32 u; } x; x.f = f;
    u32 u = x.u;
    u32 r = u + 0x7fffu + ((u >> 16) & 1u);
    return (u16)(r >> 16);
}
__device__ __forceinline__ float bf2f(u16 h) {
    union { u32 u; float f; } x; x.u = ((u32)h) << 16;
    return x.f;
}

union U8 { uint4 v; u16 h[8]; };
union U4 { uint2 v; u16 h[4]; };

// async global->LDS, 16B per lane, LDS dest = base + lane*16 (HW-fixed);
// the GLOBAL address is per-lane (gather allowed).
#define GL16(gp, lp) __builtin_amdgcn_global_load_lds( \
    (const __attribute__((address_space(1))) u32*)(gp), \
    (__attribute__((address_space(3))) u32*)(lp), 16, 0, 0)

// ===== m97-style GEMM, 128x64 tile, GL16 staging, 2 k-steps per barrier =====
// 256 threads = 4 waves (2x2). Per iteration: issue BOTH ping-pong stages'
// GL16s (latency amortized over 2 k-steps of MFMA), one barrier, compute
// both, barrier. N-fastest + bijective XCD swizzle. Swapped-operand MFMA.
// DSRC 0: single linear A (stride LDA).
// DSRC 2: fused bond-message A: acc = amsg[i1[r]]@W - msg[r^1]@W via TWO
//         MFMAs (second with sign-negated B frag); gathered rows via GL16.
// EP 1: O1=bf16(acc)
// EP 3: O1=bf16(relu(acc + (col<Nout?bias:0)))
// EP 4: merged head via LDS-bounce: col<133 -> F1=acc+bias[col];
//       133<=col<147 -> F2[row*16+col-133]=acc+bias2[col-133]
// EP 5: O1=bf16(relu(acc + inp_in))    (msg epilogue, post-relu store)
// EP 6: O1=bf16(acc); O2=bf16(relu(acc))   (W_i dual store)
template<int DSRC, int EP, int KSTEPS, int LDA, int NB>
__global__ __launch_bounds__(256, 4) void k_gemmG(
    const u16* __restrict__ A, const u16* __restrict__ Y,
    const int* __restrict__ i1, int M,
    const u16* __restrict__ Bt, int ldb, int Nout,
    const float* __restrict__ bias, const float* __restrict__ bias2,
    u16* __restrict__ O1, u16* __restrict__ O2,
    float* __restrict__ F1, float* __restrict__ F2,
    const u16* __restrict__ inp_in, int nwg)
{
    // per-buffer u16 count: DSRC0: A 128x32 + B 64x32 = 6144; DSRC2: +Y = 10240
    constexpr int SMU = (DSRC == 2) ? 10240 : 6144;
    __shared__ __align__(16) u16 SM[2 * SMU];

    // bijective XCD-chunk swizzle (m204)
    const int bid = blockIdx.x;
    const int q = nwg >> 3, r = nwg & 7;
    const int xcd = bid & 7, sidx = bid >> 3;
    const int wg = (xcd < r ? xcd * (q + 1) : r * (q + 1) + (xcd - r) * q) + sidx;

    const int n0 = (wg % NB) * 64;
    const int row0 = (wg / NB) * 128;

    const int tid = threadIdx.x;
    const int lane = tid & 63;
    const int wv = tid >> 6;
    const int wr = wv >> 1, wc = wv & 1;
    const int lrow = lane & 15;
    const int g = lane >> 4;

    // staging lane map: one GL16 covers 16 rows; lane l -> row +(l>>2), chunk l&3
    const int lr = lane >> 2, lc = lane & 3;
    int arow0 = row0 + wv * 32 + lr;
    int arow1 = arow0 + 16;
    if (arow0 >= M) arow0 = M - 1;
    if (arow1 >= M) arow1 = M - 1;

    const u16* gA0; const u16* gA1;
    const u16* gY0 = nullptr; const u16* gY1 = nullptr;
    if constexpr (DSRC == 2) {
        gA0 = A + (size_t)i1[arow0] * HP + lc * 8;   // gathered amsg rows
        gA1 = A + (size_t)i1[arow1] * HP + lc * 8;
        gY0 = Y + (size_t)(arow0 ^ 1) * HP + lc * 8; // reverse-bond msg rows
        gY1 = Y + (size_t)(arow1 ^ 1) * HP + lc * 8;
    } else {
        gA0 = A + (size_t)arow0 * LDA + lc * 8;
        gA1 = A + (size_t)arow1 * LDA + lc * 8;
    }
    const u16* gB = Bt + (size_t)(n0 + wv * 16 + lr) * ldb + lc * 8;

    constexpr int BOFF = (DSRC == 2) ? 8192 : 4096;

    // EP5: pre-issue epilogue inp loads (oldest in queue; drained by 1st sync)
    U4 ii[8];
    if constexpr (EP == 5) {
#pragma unroll
        for (int m = 0; m < 4; m++) {
            const int row = row0 + wr * 64 + m * 16 + lrow;
#pragma unroll
            for (int n = 0; n < 2; n++) {
                if (row < M)
                    ii[m * 2 + n].v = *(const uint2*)&inp_in[
                        (size_t)row * HP + n0 + wc * 32 + n * 16 + g * 4];
            }
        }
    }

    f32x4 acc[4][2] = {};

    auto STAGE = [&](int p, int ks) {
        const int k0 = ks * 32;
        u16* base = SM + p * SMU;
        GL16(gA0 + k0, base + wv * 1024);
        GL16(gA1 + k0, base + wv * 1024 + 512);
        if constexpr (DSRC == 2) {
            GL16(gY0 + k0, base + 4096 + wv * 1024);
            GL16(gY1 + k0, base + 4096 + wv * 1024 + 512);
        }
        GL16(gB + k0, base + BOFF + wv * 512);
    };

    auto COMPUTE = [&](int p) {
        const u16* base = SM + p * SMU;
        bf16x8 bfr[2];
#pragma unroll
        for (int n = 0; n < 2; n++)
            bfr[n] = *(const bf16x8*)&base[BOFF + (wc * 32 + n * 16 + lrow) * 32 + g * 8];
        bf16x8 af[4];
#pragma unroll
        for (int m = 0; m < 4; m++)
            af[m] = *(const bf16x8*)&base[(wr * 64 + m * 16 + lrow) * 32 + g * 8];
        if constexpr (DSRC == 2) {
            bf16x8 yf[4], bneg[2];
#pragma unroll
            for (int m = 0; m < 4; m++)
                yf[m] = *(const bf16x8*)&base[4096 + (wr * 64 + m * 16 + lrow) * 32 + g * 8];
#pragma unroll
            for (int n = 0; n < 2; n++) {
                uint4 bu = *(uint4*)&bfr[n];
                bu.x ^= 0x80008000u; bu.y ^= 0x80008000u;
                bu.z ^= 0x80008000u; bu.w ^= 0x80008000u;
                bneg[n] = *(bf16x8*)&bu;
            }
#pragma unroll
            for (int m = 0; m < 4; m++)
#pragma unroll
                for (int n = 0; n < 2; n++) {
                    acc[m][n] = __builtin_amdgcn_mfma_f32_16x16x32_bf16(bfr[n], af[m], acc[m][n], 0, 0, 0);
                    acc[m][n] = __builtin_amdgcn_mfma_f32_16x16x32_bf16(bneg[n], yf[m], acc[m][n], 0, 0, 0);
                }
        } else {
#pragma unroll
            for (int m = 0; m < 4; m++)
#pragma unroll
                for (int n = 0; n < 2; n++)
                    acc[m][n] = __builtin_amdgcn_mfma_f32_16x16x32_bf16(bfr[n], af[m], acc[m][n], 0, 0, 0);
        }
    };

#pragma unroll
    for (int ks = 0; ks < KSTEPS; ks += 2) {
        STAGE(0, ks);
        if (ks + 1 < KSTEPS) STAGE(1, ks + 1);
        __syncthreads();
        COMPUTE(0);
        if (ks + 1 < KSTEPS) COMPUTE(1);
        __syncthreads();
    }

    if constexpr (EP == 4) {
        // LDS-bounce coalesced f32 epilogue: 32x64 slice per m, stride 68
        float* LDSf = (float*)SM;   // 8704 B fits
#pragma unroll
        for (int m = 0; m < 4; m++) {
            __syncthreads();
#pragma unroll
            for (int n = 0; n < 2; n++)
                *(f32x4*)&LDSf[(size_t)(wr * 16 + lrow) * 68 + wc * 32 + n * 16 + g * 4] = acc[m][n];
            __syncthreads();
#pragma unroll
            for (int i = 0; i < 8; i++) {
                const int rl = wv + i * 4;                       // 0..31
                const int grow = row0 + ((rl & 16) ? 64 : 0) + m * 16 + (rl & 15);
                const float v = LDSf[(size_t)rl * 68 + lane];
                const int col = n0 + lane;                       // lane = column
                if (grow < M) {
                    if (col < 133) F1[(size_t)grow * 133 + col] = v + bias[col];
                    else if (col < 147) F2[(size_t)grow * 16 + (col - 133)] = v + bias2[col - 133];
                }
            }
        }
    } else {
#pragma unroll
        for (int m = 0; m < 4; m++) {
            const int row = row0 + wr * 64 + m * 16 + lrow;
            if (row >= M) continue;
#pragma unroll
            for (int n = 0; n < 2; n++) {
                const int colb = n0 + wc * 32 + n * 16 + g * 4;
                U4 o;
                if constexpr (EP == 1) {
#pragma unroll
                    for (int qq = 0; qq < 4; qq++) o.h[qq] = f2bf(acc[m][n][qq]);
                    *(uint2*)&O1[(size_t)row * HP + colb] = o.v;
                } else if constexpr (EP == 5) {
#pragma unroll
                    for (int qq = 0; qq < 4; qq++)
                        o.h[qq] = f2bf(fmaxf(acc[m][n][qq] + bf2f(ii[m * 2 + n].h[qq]), 0.f));
                    *(uint2*)&O1[(size_t)row * HP + colb] = o.v;
                } else if constexpr (EP == 6) {
                    U4 o2;
#pragma unroll
                    for (int qq = 0; qq < 4; qq++) {
                        o.h[qq] = f2bf(acc[m][n][qq]);
                        o2.h[qq] = f2bf(fmaxf(acc[m][n][qq], 0.f));
                    }
                    *(uint2*)&O1[(size_t)row * HP + colb] = o.v;
                    *(uint2*)&O2[(size_t)row * HP + colb] = o2.v;
                } else {
#pragma unroll
                    for (int qq = 0; qq < 4; qq++) {
                        float x = acc[m][n][qq] + ((colb + qq) < Nout ? bias[colb + qq] : 0.f);
                        o.h[qq] = f2bf(fmaxf(x, 0.f));
                    }
                    *(uint2*)&O1[(size_t)row * HP + colb] = o.v;
                }
            }
        }
    }
}

// ---------------- weight pack: Bt[n][k] = W[k][n], bf16, zero-padded ----------------
__global__ void k_pack_wt(const float* __restrict__ W, u16* __restrict__ Bt,
                          int K, int N, int Kp, int Np)
{
    int idx = blockIdx.x * 256 + threadIdx.x;
    if (idx >= Np * Kp) return;
    int n = idx / Kp, k = idx - n * Kp;
    Bt[idx] = (n < N && k < K) ? f2bf(W[(size_t)k * N + n]) : (u16)0;
}

// W_o pack with the [amsg(300) | pad4 | f_atoms(133) | pad] column reorder
__global__ void k_pack_wo(const float* __restrict__ W, u16* __restrict__ Bt)
{
    int idx = blockIdx.x * 256 + threadIdx.x;
    if (idx >= 320 * CATP) return;
    int n = idx / CATP, k = idx - n * CATP;
    float v = 0.f;
    if (n < HIDDEN) {
        if (k < HIDDEN) v = W[(size_t)(ATOM_FDIM + k) * HIDDEN + n];
        else if (k >= 304 && k < 304 + ATOM_FDIM) v = W[(size_t)(k - 304) * HIDDEN + n];
    }
    Bt[idx] = f2bf(v);
}

// merged head pack: Bt_ne[n][k]: n<133 from W_node, 133<=n<147 from W_edge
__global__ void k_pack_wne(const float* __restrict__ Wn, const float* __restrict__ We,
                           u16* __restrict__ Bt)
{
    int idx = blockIdx.x * 256 + threadIdx.x;
    if (idx >= 320 * 320) return;
    int n = idx / 320, k = idx - n * 320;
    float v = 0.f;
    if (k < HIDDEN) {
        if (n < ATOM_FDIM) v = Wn[(size_t)k * ATOM_FDIM + n];
        else if (n < ATOM_FDIM + 14) v = We[(size_t)k * 14 + (n - ATOM_FDIM)];
    }
    Bt[idx] = f2bf(v);
}

// ---------------- f_bonds fp32 [B][147] -> bf16 [B][160] ----------------
__global__ __launch_bounds__(256) void k_pack_bonds(const float* __restrict__ fb, u16* __restrict__ out)
{
    int idx = blockIdx.x * 256 + threadIdx.x;
    if (idx >= N_BONDS * 20) return;
    int b = idx / 20, c0 = (idx - b * 20) * 8;
    U8 u;
#pragma unroll
    for (int e = 0; e < 8; e++) {
        int col = c0 + e;
        u.h[e] = (col < BOND_FDIM) ? f2bf(fb[(size_t)b * BOND_FDIM + col]) : (u16)0;
    }
    *(uint4*)&out[(size_t)b * 160 + c0] = u.v;
}

// --------- a_msg[a] = sum_j msg[a2b[a][j]] (plain sum, msg is post-relu) ---------
// OST 320: plain amsg. OST 448 + FA: catbuf with f_atoms cols fused.
template<int OST, int FA>
__global__ __launch_bounds__(256) void k_aggregate(const u16* __restrict__ msg,
    const int* __restrict__ a2b, const float* __restrict__ fa, u16* __restrict__ out)
{
    constexpr int CH = FA ? 56 : 40;
    int idx = blockIdx.x * 256 + threadIdx.x;
    if (idx >= N_ATOMS * CH) return;
    int a = idx / CH, cc = idx - a * CH;
    if (FA && cc >= 38) {
        int c0 = cc * 8;     // cols 304..447: bf16 f_atoms (133) then zeros
        U8 u;
#pragma unroll
        for (int e = 0; e < 8; e++) {
            int fc = c0 + e - 304;
            u.h[e] = (fc >= 0 && fc < ATOM_FDIM) ? f2bf(fa[(size_t)a * ATOM_FDIM + fc]) : (u16)0;
        }
        *(uint4*)&out[(size_t)a * OST + c0] = u.v;
        return;
    }
    int c = cc * 8;
    float s[8] = {};
#pragma unroll
    for (int j = 0; j < 6; j++) {
        int b = a2b[a * 6 + j];
        U8 u; u.v = *(const uint4*)&msg[(size_t)b * HP + c];
#pragma unroll
        for (int i = 0; i < 8; i++) s[i] += bf2f(u.h[i]);
    }
    U8 o;
#pragma unroll
    for (int i = 0; i < 8; i++) o.h[i] = f2bf(s[i]);
    *(uint4*)&out[(size_t)a * OST + c] = o.v;
}

// -------- edge head finish: out[e] = 0.5*(E[b2a[2e]] + E[b2a[2e+1]]) --------
__global__ __launch_bounds__(256) void k_edge(const float* __restrict__ E,
    const int* __restrict__ b2a, float* __restrict__ out)
{
    int idx = blockIdx.x * 256 + threadIdx.x;
    if (idx >= N_EDGES * 7) return;
    int e = idx / 7, p = idx - e * 7;
    int a1 = b2a[2 * e], a2 = b2a[2 * e + 1];
    float2 x = *(const float2*)&E[(size_t)a1 * 16 + 2 * p];
    float2 y = *(const float2*)&E[(size_t)a2 * 16 + 2 * p];
    float2 o; o.x = 0.5f * (x.x + y.x); o.y = 0.5f * (x.y + y.y);
    *(float2*)&out[(size_t)e * 14 + 2 * p] = o;
}

// ---------------- per-molecule segment sum (graph_idx sorted) ----------------
__device__ __forceinline__ int lower_bound_i(const int* a, int n, int v) {
    int lo = 0, hi = n;
    while (lo < hi) { int mid = (lo + hi) >> 1; if (a[mid] < v) lo = mid + 1; else hi = mid; }
    return lo;
}
__global__ __launch_bounds__(320) void k_segsum(const u16* __restrict__ ah,
    const int* __restrict__ gidx, float* __restrict__ gemb)
{
    int g = blockIdx.x;
    int c = threadIdx.x;
    int s = lower_bound_i(gidx, N_ATOMS, g);
    int e = lower_bound_i(gidx, N_ATOMS, g + 1);
    float sum = 0.f;
    for (int a = s; a < e; a++) sum += bf2f(ah[(size_t)a * HP + c]);
    gemb[(size_t)g * HP + c] = sum;
}

// ---------------- graph head (fp32) ----------------
__global__ __launch_bounds__(320) void k_g1(const float* __restrict__ gemb,
    const float* __restrict__ W, const float* __restrict__ b, float* __restrict__ gh)
{
    int g = blockIdx.x, j = threadIdx.x;
    float acc = 0.f;
    if (j < HIDDEN) {
        acc = b[j];
        for (int k = 0; k < HIDDEN; k++)
            acc = fmaf(gemb[(size_t)g * HP + k], W[(size_t)k * HIDDEN + j], acc);
        acc = fmaxf(acc, 0.f);
    }
    gh[(size_t)g * HP + j] = (j < HIDDEN) ? acc : 0.f;
}
__global__ __launch_bounds__(64) void k_g2(const float* __restrict__ gh,
    const float* __restrict__ W, const float* __restrict__ b, float* __restrict__ out)
{
    int g = blockIdx.x, l = threadIdx.x;
    float acc = 0.f;
    for (int j = l; j < HIDDEN; j += 64) acc += gh[(size_t)g * HP + j] * W[j];
#pragma unroll
    for (int off = 32; off; off >>= 1) acc += __shfl_down(acc, off, 64);
    if (l == 0) out[g] = acc + b[0];
}

extern "C" void kernel_launch(void* const* d_in, const int* in_sizes, int n_in,
                              void* d_out, int out_size, void* d_ws, size_t ws_size,
                              hipStream_t stream)
{
    const float* f_atoms = (const float*)d_in[0];
    const float* f_bonds = (const float*)d_in[1];
    const int* a2b    = (const int*)d_in[2];
    const int* b2a    = (const int*)d_in[3];
    const int* gidx   = (const int*)d_in[5];
    const float* W_i    = (const float*)d_in[6];
    const float* W_h    = (const float*)d_in[7];
    const float* W_o    = (const float*)d_in[8];
    const float* b_o    = (const float*)d_in[9];
    const float* W_node = (const float*)d_in[10];
    const float* b_node = (const float*)d_in[11];
    const float* W_edge = (const float*)d_in[12];
    const float* b_edge = (const float*)d_in[13];
    const float* W_g1   = (const float*)d_in[14];
    const float* b_g1   = (const float*)d_in[15];
    const float* W_g2   = (const float*)d_in[16];
    const float* b_g2   = (const float*)d_in[17];

    char* ws = (char*)d_ws;
    u16* inp   = (u16*)(ws + 0);            // 128 MB: inp (pre-relu); later catbuf
    u16* msgA  = (u16*)(ws + 128000000);    // 128 MB: fb16 -> msg1 -> msg3
    u16* msgB  = (u16*)(ws + 256000000);    // 128 MB: msg2 -> ah
    u16* amsg  = (u16*)(ws + 384000000);    // 64 MB: amsg -> Ebuf
    u16* wt_i  = (u16*)(ws + 448000000);    // 320x160
    u16* wt_h  = (u16*)(ws + 448200000);    // 320x320
    u16* wt_o  = (u16*)(ws + 448500000);    // 320x448
    u16* wt_ne = (u16*)(ws + 448800000);    // 320x320
    float* gemb = (float*)(ws + 449300000); // 2000x320 f32
    float* gh   = (float*)(ws + 452000000); // 2000x320 f32

    float* out_node  = (float*)d_out;
    float* out_edge  = out_node + (size_t)N_ATOMS * ATOM_FDIM;
    float* out_graph = out_node + 14700000;

    dim3 blk(256);

    // pack weights (bf16, transposed, zero-padded)
    k_pack_wt<<<(320 * 160 + 255) / 256, blk, 0, stream>>>(W_i, wt_i, BOND_FDIM, HIDDEN, 160, 320);
    k_pack_wt<<<(320 * 320 + 255) / 256, blk, 0, stream>>>(W_h, wt_h, HIDDEN, HIDDEN, 320, 320);
    k_pack_wo<<<(320 * CATP + 255) / 256, blk, 0, stream>>>(W_o, wt_o);
    k_pack_wne<<<(320 * 320 + 255) / 256, blk, 0, stream>>>(W_node, W_edge, wt_ne);

    const int mbB = (N_BONDS + 127) / 128;  // 1563
    const int mbA = (N_ATOMS + 127) / 128;  // 782
    const int gAg = (N_ATOMS * 40 + 255) / 256;
    const int gAgF = (N_ATOMS * 56 + 255) / 256;
    const int nwgI = 5 * mbB;
    const int nwgO = 5 * mbA;
    const int nwgH = 3 * mbA;

    // pack f_bonds -> bf16[200k][160] into msgB (dead until msg2 written)
    u16* fb16 = msgB;
    k_pack_bonds<<<(N_BONDS * 20 + 255) / 256, blk, 0, stream>>>(f_bonds, fb16);

    // W_i dual-store: inp = f_bonds@W_i (pre-relu), msg1 = relu(inp)
    u16* msg1 = msgA;
    k_gemmG<0, 6, 5, 160, 5><<<nwgI, blk, 0, stream>>>(
        fb16, nullptr, nullptr, N_BONDS, wt_i, 160, 0, nullptr, nullptr,
        inp, msg1, nullptr, nullptr, nullptr, nwgI);

    // depth 1: amsg = sum msg1[a2b]; msg2 = relu(inp + amsg[b2a]@W - msg1[b^1]@W)
    k_aggregate<HP, 0><<<gAg, blk, 0, stream>>>(msg1, a2b, nullptr, amsg);
    u16* msg2 = msgB;
    k_gemmG<2, 5, 10, HP, 5><<<nwgI, blk, 0, stream>>>(
        amsg, msg1, b2a, N_BONDS, wt_h, 320, 0, nullptr, nullptr,
        msg2, nullptr, nullptr, nullptr, inp, nwgI);

    // depth 2: msg3 into msgA (msg1 dead)
    k_aggregate<HP, 0><<<gAg, blk, 0, stream>>>(msg2, a2b, nullptr, amsg);
    u16* msg3 = msgA;
    k_gemmG<2, 5, 10, HP, 5><<<nwgI, blk, 0, stream>>>(
        amsg, msg2, b2a, N_BONDS, wt_h, 320, 0, nullptr, nullptr,
        msg3, nullptr, nullptr, nullptr, inp, nwgI);

    // final aggregate -> catbuf (stride 448) with fused f_atoms fill
    u16* catbuf = inp;   // inp dead after depth-2 GEMM
    k_aggregate<CATP, 1><<<gAgF, blk, 0, stream>>>(msg3, a2b, f_atoms, catbuf);

    // atom_hiddens = relu(cat @ W_o + b_o) -> ah (bf16) in msgB
    u16* ah = msgB;
    k_gemmG<0, 3, 14, 448, 5><<<nwgO, blk, 0, stream>>>(
        catbuf, nullptr, nullptr, N_ATOMS, wt_o, CATP, HIDDEN, b_o, nullptr,
        ah, nullptr, nullptr, nullptr, nullptr, nwgO);

    // merged node+edge head: cols 0..132 -> node preds, 133..146 -> E buffer
    float* Ebuf = (float*)amsg;   // amsg dead after depth-2 GEMM
    k_gemmG<0, 4, 10, HP, 3><<<nwgH, blk, 0, stream>>>(
        ah, nullptr, nullptr, N_ATOMS, wt_ne, 320, 0, b_node, b_edge,
        nullptr, nullptr, out_node, Ebuf, nullptr, nwgH);

    // edge head finish: average endpoint E rows
    k_edge<<<(N_EDGES * 7 + 255) / 256, blk, 0, stream>>>(Ebuf, b2a, out_edge);

    // graph head
    k_segsum<<<N_MOLS, 320, 0, stream>>>(ah, gidx, gemb);
    k_g1<<<N_MOLS, 320, 0, stream>>>(gemb, W_g1, b_g1, gh);
    k_g2<<<N_MOLS, 64, 0, stream>>>(gh, W_g2, b_g2, out_graph);
}